// Round 6
// baseline (556.370 us; speedup 1.0000x reference)
//
#include <hip/hip_runtime.h>

// Fused ragged gather + segment-mean (sorted segment_ids).
// d_in[0] char_ids i32[8e6], d_in[1] segment_ids i32[8e6] sorted,
// d_in[2] num_words i32[1] (host uses out_size/50), d_in[3] table f32[256*50].
// Out: f32[num_words, 50].
//
// v4: ONE WORD PER WAVE. All control state (w, s, e, char ids) is wave-uniform
// and pinned to SGPRs via readfirstlane -> bounds logic on SALU, ~2 VALU + 1
// ds_read_b32 per char. Lane k (k<50) owns output float k of the word.

#define NB 256
#define EMB 50
#define BLK 1024          // 16 waves/block; 2 blocks/CU with 50KB LDS = 100% occ cap
#define WPB (BLK / 64)    // waves per block

// ---- K1: starts[w] = lower_bound(seg, w), w in [0, nw]; 4 chars/thread ----
__global__ __launch_bounds__(256) void seg_starts4(
    const int* __restrict__ seg, int* __restrict__ starts, int n, int nw) {
  int base = (blockIdx.x * blockDim.x + threadIdx.x) * 4;
  if (base >= n) return;
  int lim = n - base; if (lim > 4) lim = 4;
  int vals[4];
  if (lim == 4) {
    int4 v = *(const int4*)(seg + base);
    vals[0] = v.x; vals[1] = v.y; vals[2] = v.z; vals[3] = v.w;
  } else {
    for (int u = 0; u < lim; ++u) vals[u] = seg[base + u];
  }
  int prev = (base > 0) ? seg[base - 1] : -1;
  for (int u = 0; u < lim; ++u) {
    int cur = vals[u];
    for (int w = prev + 1; w <= cur; ++w) starts[w] = base + u;
    prev = cur;
  }
  if (base + lim == n) {                      // sentinel + trailing empty words
    for (int w = prev + 1; w <= nw; ++w) starts[w] = n;
  }
}

#define RFL(x) __builtin_amdgcn_readfirstlane(x)

// ---- K2: one word per wave, LDS table, scalar (SGPR) char pipeline ----
__global__ __launch_bounds__(BLK) void word_mean_v4(
    const int* __restrict__ char_ids, const float* __restrict__ table,
    const int* __restrict__ starts, float* __restrict__ out, int num_words) {
  __shared__ __align__(16) float tab[NB * EMB];   // 51200 B
  for (int idx = threadIdx.x; idx < NB * EMB / 4; idx += BLK)
    ((float4*)tab)[idx] = ((const float4*)table)[idx];
  __syncthreads();

  const int lane = threadIdx.x & 63;
  const int k    = (lane < EMB) ? lane : (EMB - 1);  // tail lanes alias float 49 (broadcast, free)
  const int wid0 = RFL(blockIdx.x * WPB + (threadIdx.x >> 6));
  const int nwv  = gridDim.x * WPB;

  for (int w = wid0; w < num_words; w += nwv) {
    const int s = RFL(starts[w]);
    const int e = RFL(starts[w + 1]);
    float acc = 0.f;
    int i = s;

    // 8-char batch: 8 independent (scalar) id loads, 8 independent LDS reads.
    for (; i + 8 <= e; i += 8) {
      int c0 = RFL(char_ids[i + 0]); int c1 = RFL(char_ids[i + 1]);
      int c2 = RFL(char_ids[i + 2]); int c3 = RFL(char_ids[i + 3]);
      int c4 = RFL(char_ids[i + 4]); int c5 = RFL(char_ids[i + 5]);
      int c6 = RFL(char_ids[i + 6]); int c7 = RFL(char_ids[i + 7]);
      // sequential adds in i order => bitwise-matches reference accumulation
      acc += tab[c0 * EMB + k]; acc += tab[c1 * EMB + k];
      acc += tab[c2 * EMB + k]; acc += tab[c3 * EMB + k];
      acc += tab[c4 * EMB + k]; acc += tab[c5 * EMB + k];
      acc += tab[c6 * EMB + k]; acc += tab[c7 * EMB + k];
    }
    // 4-char batch (covers ~half of words; Poisson(5) lengths)
    if (i + 4 <= e) {
      int c0 = RFL(char_ids[i + 0]); int c1 = RFL(char_ids[i + 1]);
      int c2 = RFL(char_ids[i + 2]); int c3 = RFL(char_ids[i + 3]);
      acc += tab[c0 * EMB + k]; acc += tab[c1 * EMB + k];
      acc += tab[c2 * EMB + k]; acc += tab[c3 * EMB + k];
      i += 4;
    }
    // tail 0..3
    for (; i < e; ++i) {
      int c = RFL(char_ids[i]);
      acc += tab[c * EMB + k];
    }

    const int cnt = e - s;
    const float inv = (cnt > 0) ? (1.0f / (float)cnt) : 0.0f;  // empty -> zeros
    if (lane < EMB) out[(size_t)w * EMB + lane] = acc * inv;
  }
}

// ---- fallback (ws too small): per-word binary search ----
__device__ __forceinline__ int lb(const int* __restrict__ seg, int n, int w) {
  int lo = 0, hi = n;
  while (lo < hi) { int m = (lo + hi) >> 1; if (seg[m] < w) lo = m + 1; else hi = m; }
  return lo;
}
__global__ __launch_bounds__(256) void word_mean_bs_kernel(
    const int* __restrict__ char_ids, const int* __restrict__ seg,
    const float* __restrict__ table, float* __restrict__ out, int n, int num_words) {
  int w = blockIdx.x * blockDim.x + threadIdx.x;
  if (w >= num_words) return;
  int s = lb(seg, n, w), e = lb(seg, n, w + 1);
  float ax[25], ay[25];
#pragma unroll
  for (int p = 0; p < 25; ++p) { ax[p] = 0.f; ay[p] = 0.f; }
  for (int i = s; i < e; ++i) {
    const float2* row = (const float2*)(table + char_ids[i] * EMB);
#pragma unroll
    for (int p = 0; p < 25; ++p) { float2 v = row[p]; ax[p] += v.x; ay[p] += v.y; }
  }
  int cnt = e - s;
  float inv = (cnt > 0) ? (1.0f / (float)cnt) : 0.0f;
  float2* orow = (float2*)(out + (size_t)w * EMB);
#pragma unroll
  for (int p = 0; p < 25; ++p) orow[p] = make_float2(ax[p] * inv, ay[p] * inv);
}

extern "C" void kernel_launch(void* const* d_in, const int* in_sizes, int n_in,
                              void* d_out, int out_size, void* d_ws, size_t ws_size,
                              hipStream_t stream) {
  const int*   char_ids = (const int*)d_in[0];
  const int*   seg      = (const int*)d_in[1];
  const float* table    = (const float*)d_in[3];
  float*       out      = (float*)d_out;

  const int n  = in_sizes[0];       // 8,000,000
  const int nw = out_size / EMB;    // 1,600,000

  if (ws_size >= (size_t)(nw + 1) * sizeof(int)) {
    int* starts = (int*)d_ws;
    int nchunk = (n + 3) / 4;
    seg_starts4<<<(nchunk + 255) / 256, 256, 0, stream>>>(seg, starts, n, nw);
    word_mean_v4<<<512, BLK, 0, stream>>>(char_ids, table, starts, out, nw);
  } else {
    word_mean_bs_kernel<<<(nw + 255) / 256, 256, 0, stream>>>(
        char_ids, seg, table, out, n, nw);
  }
}

// Round 8
// 493.471 us; speedup vs baseline: 1.1275x; 1.1275x over previous
//
#include <hip/hip_runtime.h>

// Fused ragged gather + segment-mean (sorted segment_ids).
// d_in[0] char_ids i32[8e6], d_in[1] segment_ids i32[8e6] sorted,
// d_in[2] num_words i32[1] (host uses out_size/50), d_in[3] table f32[256*50].
// Out: f32[num_words, 50].
//
// v5: wave owns 16 CONTIGUOUS words. starts for the group come from one
// coalesced load (readlane per word); chars stream through a 128-int register
// window (cv0/cv1) loaded coalesced ahead of use. Per char: readlane + addr
// add + ds_read_b32 + v_add_f32. All control flow wave-uniform (SALU).

#define NB 256
#define EMB 50
#define BLK 1024          // 16 waves/block; 51200B LDS -> 2 blocks/CU
#define WPB (BLK / 64)
#define WG 16             // words per wave-group

#define RL(v, l) __builtin_amdgcn_readlane((v), (l))

// ---- K1: starts[w] = lower_bound(seg, w), w in [0, nw]; 4 chars/thread ----
__global__ __launch_bounds__(256) void seg_starts4(
    const int* __restrict__ seg, int* __restrict__ starts, int n, int nw) {
  int base = (blockIdx.x * blockDim.x + threadIdx.x) * 4;
  if (base >= n) return;
  int lim = n - base; if (lim > 4) lim = 4;
  int vals[4];
  if (lim == 4) {
    int4 v = *(const int4*)(seg + base);
    vals[0] = v.x; vals[1] = v.y; vals[2] = v.z; vals[3] = v.w;
  } else {
    for (int u = 0; u < lim; ++u) vals[u] = seg[base + u];
  }
  int prev = (base > 0) ? seg[base - 1] : -1;
  for (int u = 0; u < lim; ++u) {
    int cur = vals[u];
    for (int w = prev + 1; w <= cur; ++w) starts[w] = base + u;
    prev = cur;
  }
  if (base + lim == n) {                      // sentinel + trailing empty words
    for (int w = prev + 1; w <= nw; ++w) starts[w] = n;
  }
}

// ---- K2: contiguous-16-word groups per wave, register char window ----
__global__ __launch_bounds__(BLK) void word_mean_v5(
    const int* __restrict__ char_ids, const float* __restrict__ table,
    const int* __restrict__ starts, float* __restrict__ out,
    int num_words, int n) {
  __shared__ __align__(16) float tab[NB * EMB];   // 51200 B
  for (int idx = threadIdx.x; idx < NB * EMB / 4; idx += BLK)
    ((float4*)tab)[idx] = ((const float4*)table)[idx];
  __syncthreads();

  const int lane = threadIdx.x & 63;
  const float* tabk = tab + ((lane < EMB) ? lane : 0);  // tail lanes alias float0 (broadcast)

  const int ngroups = (num_words + WG - 1) / WG;
  const int gstep = gridDim.x * WPB;

  for (int g = blockIdx.x * WPB + (threadIdx.x >> 6); g < ngroups; g += gstep) {
    const int w0 = g * WG;
    const int wlim = min(WG, num_words - w0);

    // group boundary table: one coalesced load, then readlane (no mem on control path)
    int sv = starts[w0 + min(lane, wlim)];
    int base = RL(sv, 0);
    int i = base;

    // 128-char register window [base, base+128)
    int cv0 = char_ids[min(base + lane, n - 1)];
    int cv1 = char_ids[min(base + 64 + lane, n - 1)];

    for (int j = 0; j < wlim; ++j) {
      const int ej = RL(sv, j + 1);
      const int cnt = ej - i;
      float acc = 0.f;

      // 4-char batches (independent ds_reads, ordered adds)
      while (i + 4 <= ej) {
        int t = i - base;
        if (t >= 64) {  // rotate window; cv1 was loaded ~64 chars ago (hidden)
          base += 64; t -= 64; cv0 = cv1;
          cv1 = char_ids[min(base + 64 + lane, n - 1)];
        }
        int c0, c1, c2, c3;
        if (t <= 60) {                         // fast: batch entirely in cv0
          c0 = RL(cv0, t); c1 = RL(cv0, t + 1); c2 = RL(cv0, t + 2); c3 = RL(cv0, t + 3);
        } else {                               // straddle (rare, ~5%)
          int t0 = t & 63, t1 = (t + 1) & 63, t2 = (t + 2) & 63, t3 = (t + 3) & 63;
          c0 = (t     < 64) ? RL(cv0, t0) : RL(cv1, t0);
          c1 = (t + 1 < 64) ? RL(cv0, t1) : RL(cv1, t1);
          c2 = (t + 2 < 64) ? RL(cv0, t2) : RL(cv1, t2);
          c3 = (t + 3 < 64) ? RL(cv0, t3) : RL(cv1, t3);
        }
        float v0 = tabk[c0 * EMB], v1 = tabk[c1 * EMB];
        float v2 = tabk[c2 * EMB], v3 = tabk[c3 * EMB];
        acc += v0; acc += v1; acc += v2; acc += v3;   // i-order preserved
        i += 4;
      }
      // 2-char step
      if (i + 2 <= ej) {
        int t = i - base;
        if (t >= 64) { base += 64; t -= 64; cv0 = cv1; cv1 = char_ids[min(base + 64 + lane, n - 1)]; }
        int t0 = t & 63, t1 = (t + 1) & 63;
        int c0 = (t < 64) ? RL(cv0, t0) : RL(cv1, t0);
        int c1 = (t + 1 < 64) ? RL(cv0, t1) : RL(cv1, t1);
        float v0 = tabk[c0 * EMB], v1 = tabk[c1 * EMB];
        acc += v0; acc += v1;
        i += 2;
      }
      // last char
      if (i < ej) {
        int t = i - base;
        if (t >= 64) { base += 64; t -= 64; cv0 = cv1; cv1 = char_ids[min(base + 64 + lane, n - 1)]; }
        acc += tabk[RL(cv0, t) * EMB];
        ++i;
      }

      float inv = (cnt > 0) ? (1.0f / (float)cnt) : 0.0f;  // empty word -> zeros
      if (lane < EMB) out[(size_t)(w0 + j) * EMB + lane] = acc * inv;
    }
  }
}

// ---- fallback (ws too small): per-word binary search ----
__device__ __forceinline__ int lb(const int* __restrict__ seg, int n, int w) {
  int lo = 0, hi = n;
  while (lo < hi) { int m = (lo + hi) >> 1; if (seg[m] < w) lo = m + 1; else hi = m; }
  return lo;
}
__global__ __launch_bounds__(256) void word_mean_bs_kernel(
    const int* __restrict__ char_ids, const int* __restrict__ seg,
    const float* __restrict__ table, float* __restrict__ out, int n, int num_words) {
  int w = blockIdx.x * blockDim.x + threadIdx.x;
  if (w >= num_words) return;
  int s = lb(seg, n, w), e = lb(seg, n, w + 1);
  float ax[25], ay[25];
#pragma unroll
  for (int p = 0; p < 25; ++p) { ax[p] = 0.f; ay[p] = 0.f; }
  for (int i = s; i < e; ++i) {
    const float2* row = (const float2*)(table + char_ids[i] * EMB);
#pragma unroll
    for (int p = 0; p < 25; ++p) { float2 v = row[p]; ax[p] += v.x; ay[p] += v.y; }
  }
  int cnt = e - s;
  float inv = (cnt > 0) ? (1.0f / (float)cnt) : 0.0f;
  float2* orow = (float2*)(out + (size_t)w * EMB);
#pragma unroll
  for (int p = 0; p < 25; ++p) orow[p] = make_float2(ax[p] * inv, ay[p] * inv);
}

extern "C" void kernel_launch(void* const* d_in, const int* in_sizes, int n_in,
                              void* d_out, int out_size, void* d_ws, size_t ws_size,
                              hipStream_t stream) {
  const int*   char_ids = (const int*)d_in[0];
  const int*   seg      = (const int*)d_in[1];
  const float* table    = (const float*)d_in[3];
  float*       out      = (float*)d_out;

  const int n  = in_sizes[0];       // 8,000,000
  const int nw = out_size / EMB;    // 1,600,000

  if (ws_size >= (size_t)(nw + 1) * sizeof(int)) {
    int* starts = (int*)d_ws;
    int nchunk = (n + 3) / 4;
    seg_starts4<<<(nchunk + 255) / 256, 256, 0, stream>>>(seg, starts, n, nw);
    word_mean_v5<<<512, BLK, 0, stream>>>(char_ids, table, starts, out, nw, n);
  } else {
    word_mean_bs_kernel<<<(nw + 255) / 256, 256, 0, stream>>>(
        char_ids, seg, table, out, n, nw);
  }
}